// Round 2
// baseline (346.300 us; speedup 1.0000x reference)
//
#include <hip/hip_runtime.h>
#include <hip/hip_cooperative_groups.h>

namespace cg = cooperative_groups;

// UVCrossAttention — MI355X (gfx950), Round 5: single cooperative dispatch.
//
// R4 post-mortem: swapping fp32-VALU GEMMs for bf16-MFMA moved dur only
// 113.7 -> 111.0 µs, while every individual kernel is <40 µs (all top-5
// rocprof dispatches are the harness's ~41 µs poison fills). Estimated true
// kernel work is ~20-25 µs => the residual is per-dispatch overhead /
// serialization of 3 dependent launches. This round fuses d1|d2|d3 into ONE
// hipLaunchCooperativeKernel with two grid.sync() barriers. All phase bodies
// are byte-identical to the R4 (passing) code.
//
// Co-residency: 512 blocks x 256 thr, 64 KB static LDS -> 2 blocks/CU
// (128 <= 160 KB), __launch_bounds__(256,2) caps VGPR <= 256. 512 = 2*256 CU.

#define NQ   1024
#define NV   1024
#define ND   128
#define NP   4
#define IMG_W 32
#define IMG_H 32

typedef __attribute__((ext_vector_type(8))) short bfx8;
typedef __attribute__((ext_vector_type(4))) float f32x4;

__device__ __forceinline__ unsigned short bf_rne(float f) {
  unsigned u = __float_as_uint(f);
  return (unsigned short)((u + 0x7FFFu + ((u >> 16) & 1u)) >> 16);
}

// ---------------------------------------------------------------------------
// fp32 64x64 tile GEMM (proven) — used only for keyp (phase A).
// ---------------------------------------------------------------------------
__device__ __forceinline__ void gemm_tile64(
    const float* __restrict__ A, const float* __restrict__ B,
    int N, bool nt,
    const float* __restrict__ bias, const float* __restrict__ cvec,
    float* __restrict__ C, int m0, int n0, float* sA, float* sB) {
  const int tid = threadIdx.x;
#pragma unroll
  for (int k = 0; k < 8; ++k) {
    int c = tid + k * 256;
    int m = c & 63, e4 = c >> 6;
    const float4 v = *(const float4*)(A + (size_t)(m0 + m) * 128 + e4 * 4);
    sA[(e4 * 4 + 0) * 64 + m] = v.x;
    sA[(e4 * 4 + 1) * 64 + m] = v.y;
    sA[(e4 * 4 + 2) * 64 + m] = v.z;
    sA[(e4 * 4 + 3) * 64 + m] = v.w;
  }
  if (nt) {
#pragma unroll
    for (int k = 0; k < 8; ++k) {
      int c = tid + k * 256;
      int n = c & 63, e4 = c >> 6;
      const float4 v = *(const float4*)(B + (size_t)(n0 + n) * 128 + e4 * 4);
      sB[(e4 * 4 + 0) * 64 + n] = v.x;
      sB[(e4 * 4 + 1) * 64 + n] = v.y;
      sB[(e4 * 4 + 2) * 64 + n] = v.z;
      sB[(e4 * 4 + 3) * 64 + n] = v.w;
    }
  } else {
#pragma unroll
    for (int k = 0; k < 8; ++k) {
      int c = tid + k * 256;
      int n4 = c & 15, e = c >> 4;
      *(float4*)(sB + e * 64 + n4 * 4) =
          *(const float4*)(B + (size_t)e * N + n0 + n4 * 4);
    }
  }
  __syncthreads();

  const int tx = tid & 15, ty = tid >> 4;
  float acc[4][4] = {};
#pragma unroll 8
  for (int e = 0; e < 128; ++e) {
    const float4 a = *(const float4*)(sA + e * 64 + ty * 4);
    const float4 b = *(const float4*)(sB + e * 64 + tx * 4);
    acc[0][0] += a.x * b.x; acc[0][1] += a.x * b.y; acc[0][2] += a.x * b.z; acc[0][3] += a.x * b.w;
    acc[1][0] += a.y * b.x; acc[1][1] += a.y * b.y; acc[1][2] += a.y * b.z; acc[1][3] += a.y * b.w;
    acc[2][0] += a.z * b.x; acc[2][1] += a.z * b.y; acc[2][2] += a.z * b.z; acc[2][3] += a.z * b.w;
    acc[3][0] += a.w * b.x; acc[3][1] += a.w * b.y; acc[3][2] += a.w * b.z; acc[3][3] += a.w * b.w;
  }

  float4 bv = make_float4(0.f, 0.f, 0.f, 0.f);
  if (bias) bv = *(const float4*)(bias + n0 + tx * 4);
#pragma unroll
  for (int i = 0; i < 4; ++i) {
    const int m = m0 + ty * 4 + i;
    float cv = cvec ? cvec[m] : 0.f;
    float4 r;
    r.x = acc[i][0] + bv.x + cv;
    r.y = acc[i][1] + bv.y + cv;
    r.z = acc[i][2] + bv.z + cv;
    r.w = acc[i][3] + bv.w + cv;
    *(float4*)(C + (size_t)m * 128 + n0 + tx * 4) = r;  // keyp ldc == 128
  }
}

// ---------------------------------------------------------------------------
// 64-col transpose Wsrc[128][N] -> dst[n][128] (fp32), phase A.
// ---------------------------------------------------------------------------
__device__ __forceinline__ void transpose64(const float* __restrict__ src, int N,
                                            int n0, float* __restrict__ dst,
                                            float* lds) {
  const int tid = threadIdx.x;
#pragma unroll
  for (int it = 0; it < 8; ++it) {
    int c = tid + it * 256;          // 2048 chunks = 128 k-rows x 16 float4
    int k = c >> 4, cf = c & 15;
    float4 v = *(const float4*)(src + (size_t)k * N + n0 + cf * 4);
    lds[k * 65 + cf * 4 + 0] = v.x;
    lds[k * 65 + cf * 4 + 1] = v.y;
    lds[k * 65 + cf * 4 + 2] = v.z;
    lds[k * 65 + cf * 4 + 3] = v.w;
  }
  __syncthreads();
#pragma unroll
  for (int it = 0; it < 8; ++it) {
    int c = tid + it * 256;          // 2048 chunks = 64 n-rows x 32 float4
    int dn = c >> 5, kq = c & 31;
    float4 v;
    v.x = lds[(kq * 4 + 0) * 65 + dn];
    v.y = lds[(kq * 4 + 1) * 65 + dn];
    v.z = lds[(kq * 4 + 2) * 65 + dn];
    v.w = lds[(kq * 4 + 3) * 65 + dn];
    *(float4*)(dst + (size_t)(n0 + dn) * 128 + kq * 4) = v;
  }
}

// ---------------------------------------------------------------------------
// bf16 MFMA NT GEMM tile, 128x128, 4 waves (2x2), K=128 in 4 steps (phase B).
// LDS XOR swizzle: byte ^= (row&15)<<4.
// ---------------------------------------------------------------------------
__device__ __forceinline__ void mfma_tile128(
    const float* __restrict__ A,      // [M][128] fp32
    const float* __restrict__ B,      // [N][128] fp32 (row-major n,k)
    const float* __restrict__ bias,   // [N] or null
    const float* __restrict__ cvec,   // [M] or null
    float* __restrict__ C, int ldc,
    int m0, int n0, unsigned short* sA, unsigned short* sB) {
  const int tid = threadIdx.x;

  {
    const float* srcs[2] = {A, B};
    const int r0s[2] = {m0, n0};
    unsigned short* dsts[2] = {sA, sB};
#pragma unroll
    for (int s = 0; s < 2; ++s) {
      const float* src = srcs[s];
      const int r0 = r0s[s];
      unsigned short* dst = dsts[s];
#pragma unroll
      for (int it = 0; it < 8; ++it) {
        int c = tid + it * 256;        // 2048 chunks = 128 rows x 16
        int r = c >> 4, cc = c & 15;
        const float* p = src + (size_t)(r0 + r) * 128 + cc * 8;
        float4 f0 = *(const float4*)p;
        float4 f1 = *(const float4*)(p + 4);
        bfx8 v;
        v[0] = (short)bf_rne(f0.x); v[1] = (short)bf_rne(f0.y);
        v[2] = (short)bf_rne(f0.z); v[3] = (short)bf_rne(f0.w);
        v[4] = (short)bf_rne(f1.x); v[5] = (short)bf_rne(f1.y);
        v[6] = (short)bf_rne(f1.z); v[7] = (short)bf_rne(f1.w);
        int byte = r * 256 + ((cc * 16) ^ ((r & 15) << 4));
        *(bfx8*)((char*)dst + byte) = v;
      }
    }
  }
  __syncthreads();

  const int l = tid & 63;
  const int w = tid >> 6;
  const int wr = w >> 1, wc = w & 1;
  const int lr = l & 15, g = l >> 4;

  f32x4 acc[4][4];
#pragma unroll
  for (int mi = 0; mi < 4; ++mi)
#pragma unroll
    for (int ni = 0; ni < 4; ++ni) {
      f32x4 z = {0.f, 0.f, 0.f, 0.f};
      acc[mi][ni] = z;
    }

#pragma unroll
  for (int ks = 0; ks < 4; ++ks) {
    const int colb = (ks * 64 + g * 16) ^ (lr << 4);
    bfx8 af[4], bfr[4];
#pragma unroll
    for (int mi = 0; mi < 4; ++mi) {
      int r = wr * 64 + mi * 16 + lr;
      af[mi] = *(const bfx8*)((const char*)sA + r * 256 + colb);
    }
#pragma unroll
    for (int ni = 0; ni < 4; ++ni) {
      int r = wc * 64 + ni * 16 + lr;
      bfr[ni] = *(const bfx8*)((const char*)sB + r * 256 + colb);
    }
#pragma unroll
    for (int mi = 0; mi < 4; ++mi)
#pragma unroll
      for (int ni = 0; ni < 4; ++ni)
        acc[mi][ni] = __builtin_amdgcn_mfma_f32_16x16x32_bf16(
            af[mi], bfr[ni], acc[mi][ni], 0, 0, 0);
  }

  // C/D layout: col=lane&15, row=(lane>>4)*4+reg (HW-verified)
#pragma unroll
  for (int mi = 0; mi < 4; ++mi) {
    float cv[4];
#pragma unroll
    for (int i = 0; i < 4; ++i) {
      int row = m0 + wr * 64 + mi * 16 + g * 4 + i;
      cv[i] = cvec ? cvec[row] : 0.f;
    }
#pragma unroll
    for (int ni = 0; ni < 4; ++ni) {
      int col = n0 + wc * 64 + ni * 16 + lr;
      float bn = bias ? bias[col] : 0.f;
#pragma unroll
      for (int i = 0; i < 4; ++i) {
        int row = m0 + wr * 64 + mi * 16 + g * 4 + i;
        C[(size_t)row * ldc + col] = acc[mi][ni][i] + bn + cv[i];
      }
    }
  }
}

// ---------------------------------------------------------------------------
// Fused cooperative kernel: phase A (transposes|keyp|c) -> grid.sync ->
// phase B (off|aw|dotv MFMA GEMMs) -> grid.sync -> phase C (sample + @W_o).
// ---------------------------------------------------------------------------
__global__ __launch_bounds__(256, 2) void fused_kernel(
    const float* __restrict__ query, const float* __restrict__ key,
    const float* __restrict__ value, const float* __restrict__ ref3d,
    const float* __restrict__ W_off, const float* __restrict__ b_off,
    const float* __restrict__ W_attn, const float* __restrict__ b_attn,
    const float* __restrict__ W_v, const float* __restrict__ b_v,
    const float* __restrict__ W_o, const float* __restrict__ b_o,
    float* __restrict__ off_ws, float* __restrict__ aw_ws,
    float* __restrict__ keyp_ws, float* __restrict__ c_ws,
    float* __restrict__ dotv_ws, float* __restrict__ wofft,
    float* __restrict__ wattnt, float* __restrict__ out) {
  __shared__ __align__(16) char smem[65536];   // 64 KB union -> 2 blocks/CU
  cg::grid_group grid = cg::this_grid();
  const int b = blockIdx.x;
  const int tid = threadIdx.x;

  // ---- Phase A: blocks 0..56 --------------------------------------------
  if (b < 16) {
    transpose64(W_off, 1024, b * 64, wofft, (float*)smem);
  } else if (b < 24) {
    transpose64(W_attn, 512, (b - 16) * 64, wattnt, (float*)smem);
  } else if (b < 56) {
    const int u = b - 24;            // 32 tiles: keyp = key@W_v^T
    gemm_tile64(key, W_v, 128, true, nullptr, nullptr, keyp_ws,
                (u >> 1) * 64, (u & 1) * 64, (float*)smem,
                (float*)smem + 8192);
  } else if (b == 56) {
    for (int i = 0; i < 4; ++i) {    // c[q] = key[q]·b_v (b_v==0 here)
      const int q = tid + i * 256;
      float s = 0.f;
      for (int e = 0; e < 128; ++e) s += key[(size_t)q * 128 + e] * b_v[e];
      c_ws[q] = s;
    }
  }

  __threadfence();
  grid.sync();

  // ---- Phase B: blocks 0..159 -------------------------------------------
  {
    unsigned short* sA = (unsigned short*)smem;
    unsigned short* sB = sA + 16384;
    if (b < 64) {            // off = query @ WoffT^T + b_off   [1024][1024]
      mfma_tile128(query, wofft, b_off, nullptr, off_ws, 1024,
                   (b >> 3) * 128, (b & 7) * 128, sA, sB);
    } else if (b < 96) {     // aw = query @ WattnT^T + b_attn  [1024][512]
      const int u = b - 64;
      mfma_tile128(query, wattnt, b_attn, nullptr, aw_ws, 512,
                   (u >> 2) * 128, (u & 3) * 128, sA, sB);
    } else if (b < 160) {    // dotv = keyp @ value^T + c[m]    [1024][1024]
      const int u = b - 96;
      mfma_tile128(keyp_ws, value, nullptr, c_ws, dotv_ws, 1024,
                   (u >> 3) * 128, (u & 7) * 128, sA, sB);
    }
  }

  __threadfence();
  grid.sync();

  // ---- Phase C: all 512 blocks, block b -> queries 2b, 2b+1 -------------
  {
    float* img = (float*)smem;            // [2][1024]
    float* o1s = (float*)smem + 2048;     // [2][128]
    const int q0 = b * 2;

#pragma unroll
    for (int k = 0; k < 2; ++k) {
      int c = tid + k * 256;
      int qq = c >> 8, v4 = c & 255;
      *(float4*)(&img[qq * NV + v4 * 4]) =
          *(const float4*)(dotv_ws + (size_t)(q0 + qq) * NV + v4 * 4);
    }
    __syncthreads();

    {
      const int qq = tid >> 7;
      const int q = q0 + qq;
      const int d = tid & 127;
      const float* im = img + qq * NV;
      const size_t qe = (size_t)q * ND + d;

      const float rx = ref3d[qe * 2 + 0];
      const float ry = ref3d[qe * 2 + 1];

      const float* awp = aw_ws + (size_t)q * (ND * NP) + d * NP;
      const float a0 = awp[0], a1 = awp[1], a2 = awp[2], a3 = awp[3];
      const float mx = fmaxf(fmaxf(a0, a1), fmaxf(a2, a3));
      const float e0 = __expf(a0 - mx), e1 = __expf(a1 - mx),
                  e2 = __expf(a2 - mx), e3 = __expf(a3 - mx);
      const float inv = 1.0f / (e0 + e1 + e2 + e3);
      const float wgt4[4] = {e0 * inv, e1 * inv, e2 * inv, e3 * inv};

      const float* op = off_ws + (size_t)q * (ND * NP * 2) + d * (NP * 2);

      float acc = 0.0f;
#pragma unroll
      for (int p = 0; p < NP; ++p) {
        const float x = rx * (float)IMG_W + op[p * 2 + 0] - 0.5f;
        const float y = ry * (float)IMG_H + op[p * 2 + 1] - 0.5f;
        const float xf = floorf(x), yf = floorf(y);
        const int ix0 = (int)xf, iy0 = (int)yf;
        const float wx1 = x - xf, wy1 = y - yf;
        const float wx0 = 1.0f - wx1, wy0 = 1.0f - wy1;

        float s = 0.0f;
#pragma unroll
        for (int cy = 0; cy < 2; ++cy) {
#pragma unroll
          for (int cx = 0; cx < 2; ++cx) {
            const int ix = ix0 + cx, iy = iy0 + cy;
            const bool valid = (ix >= 0) & (ix < IMG_W) & (iy >= 0) & (iy < IMG_H);
            const int cix = min(max(ix, 0), IMG_W - 1);
            const int ciy = min(max(iy, 0), IMG_H - 1);
            const float wgt = (cx ? wx1 : wx0) * (cy ? wy1 : wy0);
            s += valid ? im[ciy * IMG_W + cix] * wgt : 0.0f;
          }
        }
        acc += wgt4[p] * s;
      }
      o1s[qq * ND + d] = acc * (1.0f / 128.0f);
    }
    __syncthreads();

    {
      const int qq = tid >> 7;
      const int q = q0 + qq;
      const int n = tid & 127;
      float acc = b_o[n] + query[(size_t)q * 128 + n];
#pragma unroll 8
      for (int d = 0; d < 128; ++d)
        acc += o1s[qq * ND + d] * W_o[(size_t)d * 128 + n];
      out[(size_t)q * 128 + n] = acc;
    }
  }
}

// ---------------------------------------------------------------------------
extern "C" void kernel_launch(void* const* d_in, const int* in_sizes, int n_in,
                              void* d_out, int out_size, void* d_ws, size_t ws_size,
                              hipStream_t stream) {
  const float* query  = (const float*)d_in[0];
  const float* key    = (const float*)d_in[1];
  const float* value  = (const float*)d_in[2];
  const float* ref3d  = (const float*)d_in[3];
  // d_in[4] = spatial_shapes [[32,32]] (hardcoded)
  const float* W_off  = (const float*)d_in[5];
  const float* b_off  = (const float*)d_in[6];
  const float* W_attn = (const float*)d_in[7];
  const float* b_attn = (const float*)d_in[8];
  const float* W_v    = (const float*)d_in[9];
  const float* b_v    = (const float*)d_in[10];
  const float* W_o    = (const float*)d_in[11];
  const float* b_o    = (const float*)d_in[12];
  float* out = (float*)d_out;

  float* ws = (float*)d_ws;
  float* off_ws  = ws;                             // 1024*1024
  float* aw_ws   = off_ws + (size_t)NQ * 1024;     // 1024*512
  float* keyp_ws = aw_ws + (size_t)NQ * 512;       // 1024*128
  float* c_ws    = keyp_ws + (size_t)NQ * 128;     // 1024
  float* dotv_ws = c_ws + 1024;                    // 1024*1024
  float* wofft   = dotv_ws + (size_t)NQ * 1024;    // 1024*128 (W_off^T)
  float* wattnt  = wofft + (size_t)1024 * 128;     // 512*128  (W_attn^T)

  void* args[] = {
      (void*)&query, (void*)&key, (void*)&value, (void*)&ref3d,
      (void*)&W_off, (void*)&b_off, (void*)&W_attn, (void*)&b_attn,
      (void*)&W_v, (void*)&b_v, (void*)&W_o, (void*)&b_o,
      (void*)&off_ws, (void*)&aw_ws, (void*)&keyp_ws, (void*)&c_ws,
      (void*)&dotv_ws, (void*)&wofft, (void*)&wattnt, (void*)&out};

  hipLaunchCooperativeKernel((const void*)fused_kernel, dim3(512), dim3(256),
                             args, 0, stream);
}

// Round 4
// 119.416 us; speedup vs baseline: 2.9000x; 2.9000x over previous
//
#include <hip/hip_runtime.h>

// UVCrossAttention — MI355X (gfx950), Round 7: single-dispatch monolith, fixed.
//
// R6 post-mortem: wave-coop loops covered only HALF the rows (keyp s<8 should
// be s<16; img s<64 should be s<128) -> absmax 31. Also, the shuffle-reduce
// dot for img costs ~86k LDS-pipe cycles/CU (~36 µs) — replaced by a thin
// MFMA: A = keyp zero-padded 4->16 rows (A-frags hoisted to registers),
// B = value staged per 64-row tile as XOR-swizzled bf16 (R4's proven NT
// pattern), D rows 0..3 = img. One dispatch, zero workspace, zero grid sync.
//
// LDS (59.4 KB static): q(2K) img(16K) off(16K) aw(8K) c(16B) + overlay
// Ru(16K): {key 2K | keyp 2K} phases 1-4a -> sval bf16[64][128] 4b -> o1s 5-6.
// 256 blocks x 256 thr = 1 block/CU; each block owns QB=4 queries end-to-end.

#define NQ   1024
#define NV   1024
#define ND   128
#define NP   4
#define IMG_W 32
#define IMG_H 32
#define QB   4

typedef __attribute__((ext_vector_type(8))) short bfx8;
typedef __attribute__((ext_vector_type(4))) float f32x4;

__device__ __forceinline__ unsigned short bf_rne(float f) {
  unsigned u = __float_as_uint(f);
  return (unsigned short)((u + 0x7FFFu + ((u >> 16) & 1u)) >> 16);
}

__global__ __launch_bounds__(256) void mono_kernel(
    const float* __restrict__ query, const float* __restrict__ key,
    const float* __restrict__ value, const float* __restrict__ ref3d,
    const float* __restrict__ W_off, const float* __restrict__ b_off,
    const float* __restrict__ W_attn, const float* __restrict__ b_attn,
    const float* __restrict__ W_v, const float* __restrict__ b_v,
    const float* __restrict__ W_o, const float* __restrict__ b_o,
    float* __restrict__ out) {
  __shared__ float q_lds[QB][128];      // 2 KB   (live 1..6)
  __shared__ float img[QB][NV];         // 16 KB  (4..5)
  __shared__ float off_lds[QB][1024];   // 16 KB  (2..5)
  __shared__ float aw_lds[QB][512];     // 8 KB   (2..5)
  __shared__ float c_lds[QB];           //        (3..4)
  __shared__ __align__(16) char Ru[16384];  // overlay region
  float* key_lds  = (float*)Ru;             // [QB][128]  (1..3)
  float* keyp_lds = (float*)(Ru + 2048);    // [QB][128]  (3..4a)
  unsigned short* sval = (unsigned short*)Ru;  // [64][128] bf16 (4b)
  float* o1s = (float*)Ru;                  // [QB][128]  (5..6)

  const int tid = threadIdx.x;
  const int q0 = blockIdx.x * QB;
  const int w = tid >> 6, l = tid & 63;

  // ---- 1. stage query & key rows (coalesced float4)
  if (tid < 128) {
    ((float4*)q_lds)[tid] = ((const float4*)(query + (size_t)q0 * 128))[tid];
  } else {
    ((float4*)key_lds)[tid - 128] =
        ((const float4*)(key + (size_t)q0 * 128))[tid - 128];
  }
  __syncthreads();

  // ---- 2. off/aw: stream W rows; thread owns off cols 4t..4t+3, aw 2t..2t+1
  {
    float4 aoff[QB];
    float2 aaw[QB];
#pragma unroll
    for (int qq = 0; qq < QB; ++qq) {
      aoff[qq] = make_float4(0.f, 0.f, 0.f, 0.f);
      aaw[qq] = make_float2(0.f, 0.f);
    }
    const float* wo_p = W_off + (size_t)tid * 4;
    const float* wa_p = W_attn + (size_t)tid * 2;
#pragma unroll 4
    for (int e4 = 0; e4 < 32; ++e4) {
      float4 q4[QB];
#pragma unroll
      for (int qq = 0; qq < QB; ++qq)
        q4[qq] = *(const float4*)(&q_lds[qq][e4 * 4]);
#pragma unroll
      for (int j = 0; j < 4; ++j) {
        const int e = e4 * 4 + j;
        const float4 w4 = *(const float4*)(wo_p + (size_t)e * 1024);
        const float2 w2 = *(const float2*)(wa_p + (size_t)e * 512);
#pragma unroll
        for (int qq = 0; qq < QB; ++qq) {
          const float* qp = (const float*)&q4[qq];
          const float qv = qp[j];               // static extract (j unrolled)
          aoff[qq].x = fmaf(qv, w4.x, aoff[qq].x);
          aoff[qq].y = fmaf(qv, w4.y, aoff[qq].y);
          aoff[qq].z = fmaf(qv, w4.z, aoff[qq].z);
          aoff[qq].w = fmaf(qv, w4.w, aoff[qq].w);
          aaw[qq].x = fmaf(qv, w2.x, aaw[qq].x);
          aaw[qq].y = fmaf(qv, w2.y, aaw[qq].y);
        }
      }
    }
    const float4 bo4 = *(const float4*)(b_off + tid * 4);
    const float2 ba2 = *(const float2*)(b_attn + tid * 2);
#pragma unroll
    for (int qq = 0; qq < QB; ++qq) {
      float4 r;
      r.x = aoff[qq].x + bo4.x; r.y = aoff[qq].y + bo4.y;
      r.z = aoff[qq].z + bo4.z; r.w = aoff[qq].w + bo4.w;
      *(float4*)(&off_lds[qq][tid * 4]) = r;
      float2 r2;
      r2.x = aaw[qq].x + ba2.x; r2.y = aaw[qq].y + ba2.y;
      *(float2*)(&aw_lds[qq][tid * 2]) = r2;
    }
  }

  // ---- 3. keyp[qq][i] = key[qq]·W_v[i]  (wave-coop, FIXED bounds: 16 steps)
  {
    const int h = l >> 5, e4s = l & 31;
#pragma unroll 2
    for (int s = 0; s < 16; ++s) {
      const int i = w * 32 + s * 2 + h;            // 4 waves x 32 rows = 128
      const float4 wv = *(const float4*)(W_v + (size_t)i * 128 + e4s * 4);
      float p[QB];
#pragma unroll
      for (int qq = 0; qq < QB; ++qq) {
        const float4 k4 = *(const float4*)(key_lds + qq * 128 + e4s * 4);
        p[qq] = fmaf(wv.x, k4.x,
                fmaf(wv.y, k4.y, fmaf(wv.z, k4.z, wv.w * k4.w)));
      }
#pragma unroll
      for (int m = 1; m < 32; m <<= 1)
#pragma unroll
        for (int qq = 0; qq < QB; ++qq) p[qq] += __shfl_xor(p[qq], m);
      if (e4s == 0)
#pragma unroll
        for (int qq = 0; qq < QB; ++qq) keyp_lds[qq * 128 + i] = p[qq];
    }
    if (tid < QB) {   // c[qq] = key[qq]·b_v (b_v == 0 here; kept for generality)
      float s = 0.f;
      for (int e = 0; e < 128; e += 4) {
        const float4 bv = *(const float4*)(b_v + e);
        const float4 k4 = *(const float4*)(key_lds + tid * 128 + e);
        s = fmaf(bv.x, k4.x,
            fmaf(bv.y, k4.y, fmaf(bv.z, k4.z, fmaf(bv.w, k4.w, s))));
      }
      c_lds[tid] = s;
    }
  }
  __syncthreads();

  // ---- 4a. hoist A-fragments (keyp rows 0..3 zero-padded to 16) to regs
  bfx8 afrag[4];
  {
    const int row = l & 15, g = l >> 4;
#pragma unroll
    for (int ks = 0; ks < 4; ++ks) {
      bfx8 a;
      if (row < QB) {
        const float* kp = keyp_lds + row * 128 + ks * 32 + g * 8;
#pragma unroll
        for (int j = 0; j < 8; ++j) a[j] = (short)bf_rne(kp[j]);
      } else {
#pragma unroll
        for (int j = 0; j < 8; ++j) a[j] = 0;
      }
      afrag[ks] = a;
    }
  }
  __syncthreads();   // keyp reads done -> Ru becomes sval

  // ---- 4b. img[qq][v] = keyp[qq]·value[v] + c[qq]  (MFMA, 16 tiles x 64 v)
  for (int vt = 0; vt < 16; ++vt) {
    // stage value[vt*64 .. +63][0..127] -> bf16 swizzled (byte ^= (r&15)<<4)
#pragma unroll
    for (int it = 0; it < 4; ++it) {
      const int c = tid + it * 256;        // 1024 chunks of 16B
      const int r = c >> 4, cc = c & 15;
      const float* p = value + (size_t)(vt * 64 + r) * 128 + cc * 8;
      const float4 f0 = *(const float4*)p;
      const float4 f1 = *(const float4*)(p + 4);
      bfx8 vv;
      vv[0] = (short)bf_rne(f0.x); vv[1] = (short)bf_rne(f0.y);
      vv[2] = (short)bf_rne(f0.z); vv[3] = (short)bf_rne(f0.w);
      vv[4] = (short)bf_rne(f1.x); vv[5] = (short)bf_rne(f1.y);
      vv[6] = (short)bf_rne(f1.z); vv[7] = (short)bf_rne(f1.w);
      const int byte = r * 256 + ((cc * 16) ^ ((r & 15) << 4));
      *(bfx8*)((char*)sval + byte) = vv;
    }
    __syncthreads();

    // wave w owns v rows w*16..w*16+15 of this tile
    {
      const int col = l & 15, g = l >> 4;
      const int r = w * 16 + col;          // B-col = value row (r&15 == col)
      f32x4 acc = {0.f, 0.f, 0.f, 0.f};
#pragma unroll
      for (int ks = 0; ks < 4; ++ks) {
        const int colb = (ks * 64 + g * 16) ^ (col << 4);
        const bfx8 bfr = *(const bfx8*)((const char*)sval + r * 256 + colb);
        acc = __builtin_amdgcn_mfma_f32_16x16x32_bf16(afrag[ks], bfr, acc,
                                                      0, 0, 0);
      }
      // D layout: col=lane&15, row=(lane>>4)*4+reg -> rows 0..3 in lanes l<16
      if (g == 0) {
        const int v = vt * 64 + w * 16 + col;
#pragma unroll
        for (int i = 0; i < QB; ++i) img[i][v] = acc[i] + c_lds[i];
      }
    }
    __syncthreads();
  }

  // ---- 5. sampling: two passes, (qq, d) = ((tid>>7)+2*pass, tid&127)
#pragma unroll
  for (int pass = 0; pass < 2; ++pass) {
    const int qq = (tid >> 7) + 2 * pass;
    const int q = q0 + qq;
    const int d = tid & 127;
    const float* im = img[qq];
    const size_t qe = (size_t)q * ND + d;

    const float rx = ref3d[qe * 2 + 0];
    const float ry = ref3d[qe * 2 + 1];

    const float* awp = &aw_lds[qq][d * NP];
    const float a0 = awp[0], a1 = awp[1], a2 = awp[2], a3 = awp[3];
    const float mx = fmaxf(fmaxf(a0, a1), fmaxf(a2, a3));
    const float e0 = __expf(a0 - mx), e1 = __expf(a1 - mx),
                e2 = __expf(a2 - mx), e3 = __expf(a3 - mx);
    const float inv = 1.0f / (e0 + e1 + e2 + e3);
    const float wgt4[4] = {e0 * inv, e1 * inv, e2 * inv, e3 * inv};

    const float* op = &off_lds[qq][d * (NP * 2)];

    float acc = 0.0f;
#pragma unroll
    for (int p = 0; p < NP; ++p) {
      const float x = rx * (float)IMG_W + op[p * 2 + 0] - 0.5f;
      const float y = ry * (float)IMG_H + op[p * 2 + 1] - 0.5f;
      const float xf = floorf(x), yf = floorf(y);
      const int ix0 = (int)xf, iy0 = (int)yf;
      const float wx1 = x - xf, wy1 = y - yf;
      const float wx0 = 1.0f - wx1, wy0 = 1.0f - wy1;

      float s = 0.0f;
#pragma unroll
      for (int cy = 0; cy < 2; ++cy) {
#pragma unroll
        for (int cx = 0; cx < 2; ++cx) {
          const int ix = ix0 + cx, iy = iy0 + cy;
          const bool valid = (ix >= 0) & (ix < IMG_W) & (iy >= 0) & (iy < IMG_H);
          const int cix = min(max(ix, 0), IMG_W - 1);
          const int ciy = min(max(iy, 0), IMG_H - 1);
          const float wgt = (cx ? wx1 : wx0) * (cy ? wy1 : wy0);
          s += valid ? im[ciy * IMG_W + cix] * wgt : 0.0f;
        }
      }
      acc += wgt4[p] * s;
    }
    o1s[qq * ND + d] = acc * (1.0f / 128.0f);   // o1s overlays dead sval
  }
  __syncthreads();

  // ---- 6. out[q][n] = o1s[q]·W_o[:,n] + b_o[n] + query[q][n]
  {
    const int qqA = tid >> 7, qqB = qqA + 2;
    const int n = tid & 127;
    float acc0 = b_o[n] + q_lds[qqA][n];
    float acc1 = b_o[n] + q_lds[qqB][n];
#pragma unroll 8
    for (int d = 0; d < 128; ++d) {
      const float wv = W_o[(size_t)d * 128 + n];   // coalesced, L2-hot
      acc0 = fmaf(o1s[qqA * ND + d], wv, acc0);
      acc1 = fmaf(o1s[qqB * ND + d], wv, acc1);
    }
    out[(size_t)(q0 + qqA) * 128 + n] = acc0;
    out[(size_t)(q0 + qqB) * 128 + n] = acc1;
  }
}

// ---------------------------------------------------------------------------
extern "C" void kernel_launch(void* const* d_in, const int* in_sizes, int n_in,
                              void* d_out, int out_size, void* d_ws, size_t ws_size,
                              hipStream_t stream) {
  const float* query  = (const float*)d_in[0];
  const float* key    = (const float*)d_in[1];
  const float* value  = (const float*)d_in[2];
  const float* ref3d  = (const float*)d_in[3];
  // d_in[4] = spatial_shapes [[32,32]] (hardcoded)
  const float* W_off  = (const float*)d_in[5];
  const float* b_off  = (const float*)d_in[6];
  const float* W_attn = (const float*)d_in[7];
  const float* b_attn = (const float*)d_in[8];
  const float* W_v    = (const float*)d_in[9];
  const float* b_v    = (const float*)d_in[10];
  const float* W_o    = (const float*)d_in[11];
  const float* b_o    = (const float*)d_in[12];
  float* out = (float*)d_out;

  mono_kernel<<<NQ / QB, 256, 0, stream>>>(query, key, value, ref3d,
                                           W_off, b_off, W_attn, b_attn,
                                           W_v, b_v, W_o, b_o, out);
}

// Round 5
// 108.199 us; speedup vs baseline: 3.2006x; 1.1037x over previous
//
#include <hip/hip_runtime.h>

// UVCrossAttention — MI355X (gfx950), Round 8: monolith, 512 threads/block.
//
// R7 post-mortem (first clean attribution): mono_kernel = 50 µs at
// VALUBusy 15% / MfmaUtil 0.8% / Occupancy 10.5% -> latency-bound at
// 1 wave/SIMD. dur_us 119.4 = fill(40) + mono(50) + ~29 fixed residue.
// This round attacks mono itself:
//   * 512 thr/block (8 waves/CU, 2/SIMD) — 2x latency hiding everywhere.
//   * keyp (phase 3) computed by the SAME thin-MFMA pattern that passed in
//     R7 phase 4b (W_v staged as 128 swizzled-bf16 rows, A = key 4->16 pad)
//     — kills the dependent __shfl_xor reduce chains.
//   * value MFMA tiles 64 -> 128 rows (8 tiles, half the barriers).
//   * off/aw/img stored bf16 in LDS to fit 59.4 KB static (<64 KB) with the
//     32 KB sval tile. Error budget: each bf16 path attenuated by /128 and
//     unit-norm W_o => ~1e-4..3e-4 added; R7 absmax 0.0156, threshold 0.0875.
// One dispatch, zero workspace, zero grid sync. 256 blocks x 512 thr.

#define NQ   1024
#define NV   1024
#define ND   128
#define NP   4
#define IMG_W 32
#define IMG_H 32
#define QB   4

typedef __attribute__((ext_vector_type(8))) short bfx8;
typedef __attribute__((ext_vector_type(4))) float f32x4;

__device__ __forceinline__ unsigned short bf_rne(float f) {
  unsigned u = __float_as_uint(f);
  return (unsigned short)((u + 0x7FFFu + ((u >> 16) & 1u)) >> 16);
}
__device__ __forceinline__ float bf2f(unsigned short u) {
  return __uint_as_float((unsigned)u << 16);
}

// pack 8 consecutive fp32 -> bfx8
__device__ __forceinline__ bfx8 pack8(const float* p) {
  bfx8 v;
#pragma unroll
  for (int j = 0; j < 8; ++j) v[j] = (short)bf_rne(p[j]);
  return v;
}

__global__ __launch_bounds__(512) void mono_kernel(
    const float* __restrict__ query, const float* __restrict__ key,
    const float* __restrict__ value, const float* __restrict__ ref3d,
    const float* __restrict__ W_off, const float* __restrict__ b_off,
    const float* __restrict__ W_attn, const float* __restrict__ b_attn,
    const float* __restrict__ W_v, const float* __restrict__ b_v,
    const float* __restrict__ W_o, const float* __restrict__ b_o,
    float* __restrict__ out) {
  __shared__ float q_lds[QB][128];                    // 2 KB   (1..6)
  __shared__ float key_lds[QB][128];                  // 2 KB   (1..3)
  __shared__ float keyp_lds[QB][128];                 // 2 KB   (3..4a)
  __shared__ float c_lds[QB];                         //        (3..4b)
  __shared__ unsigned short img_bf[QB][NV];           // 8 KB   (4b..5)
  __shared__ unsigned short off_bf[QB][1024];         // 8 KB   (2..5)
  __shared__ unsigned short aw_bf[QB][512];           // 4 KB   (2..5)
  __shared__ __align__(16) unsigned short sval[128 * 128];  // 32 KB (3,4b)
  float* o1s = (float*)sval;                          // [QB][128] (5..6) overlay

  const int tid = threadIdx.x;
  const int q0 = blockIdx.x * QB;
  const int w = tid >> 6, l = tid & 63;

  // ---- 1. stage query & key rows (QB*128 floats each, coalesced float4)
  if (tid < 128) {
    ((float4*)q_lds)[tid] = ((const float4*)(query + (size_t)q0 * 128))[tid];
  } else if (tid < 256) {
    ((float4*)key_lds)[tid - 128] =
        ((const float4*)(key + (size_t)q0 * 128))[tid - 128];
  }
  __syncthreads();

  // ---- 2. off/aw: stream W; thread owns off cols {2t,2t+1}, aw col t
  {
    float2 aoff[QB];
    float aaw[QB];
#pragma unroll
    for (int qq = 0; qq < QB; ++qq) {
      aoff[qq] = make_float2(0.f, 0.f);
      aaw[qq] = 0.f;
    }
    const float* wo_p = W_off + (size_t)tid * 2;
    const float* wa_p = W_attn + tid;
#pragma unroll 4
    for (int e4 = 0; e4 < 32; ++e4) {
      float4 q4[QB];
#pragma unroll
      for (int qq = 0; qq < QB; ++qq)
        q4[qq] = *(const float4*)(&q_lds[qq][e4 * 4]);
#pragma unroll
      for (int j = 0; j < 4; ++j) {
        const int e = e4 * 4 + j;
        const float2 w2 = *(const float2*)(wo_p + (size_t)e * 1024);
        const float wa = wa_p[(size_t)e * 512];
#pragma unroll
        for (int qq = 0; qq < QB; ++qq) {
          const float* qp = (const float*)&q4[qq];
          const float qv = qp[j];              // static extract (j unrolled)
          aoff[qq].x = fmaf(qv, w2.x, aoff[qq].x);
          aoff[qq].y = fmaf(qv, w2.y, aoff[qq].y);
          aaw[qq] = fmaf(qv, wa, aaw[qq]);
        }
      }
    }
    const float2 bo2 = *(const float2*)(b_off + tid * 2);
    const float ba = b_attn[tid];
#pragma unroll
    for (int qq = 0; qq < QB; ++qq) {
      const unsigned px = (unsigned)bf_rne(aoff[qq].x + bo2.x) |
                          ((unsigned)bf_rne(aoff[qq].y + bo2.y) << 16);
      *(unsigned*)(&off_bf[qq][tid * 2]) = px;
      aw_bf[qq][tid] = bf_rne(aaw[qq] + ba);
    }
  }

  // ---- 3. keyp = key @ W_v^T via thin MFMA (W_v staged 128 rows, swizzled)
  {
#pragma unroll
    for (int it = 0; it < 4; ++it) {
      const int c = tid + it * 512;          // 2048 chunks of 8 floats
      const int r = c >> 4, cc = c & 15;
      const bfx8 v = pack8(W_v + (size_t)r * 128 + cc * 8);
      const int byte = r * 256 + ((cc * 16) ^ ((r & 15) << 4));
      *(bfx8*)((char*)sval + byte) = v;
    }
    // A-fragments from key rows (4 real, padded to 16)
    bfx8 afK[4];
    {
      const int row = l & 15, g = l >> 4;
#pragma unroll
      for (int ks = 0; ks < 4; ++ks) {
        bfx8 a;
        if (row < QB) {
          a = pack8(&key_lds[row][ks * 32 + g * 8]);
        } else {
#pragma unroll
          for (int j = 0; j < 8; ++j) a[j] = 0;
        }
        afK[ks] = a;
      }
    }
    __syncthreads();

    {
      const int col = l & 15, g = l >> 4;
      const int r = w * 16 + col;            // W_v row = keyp embed index
      f32x4 acc = {0.f, 0.f, 0.f, 0.f};
#pragma unroll
      for (int ks = 0; ks < 4; ++ks) {
        const int colb = (ks * 64 + g * 16) ^ (col << 4);
        const bfx8 bfr = *(const bfx8*)((const char*)sval + r * 256 + colb);
        acc = __builtin_amdgcn_mfma_f32_16x16x32_bf16(afK[ks], bfr, acc,
                                                      0, 0, 0);
      }
      if (g == 0) {                          // D rows 0..3 = queries
#pragma unroll
        for (int i = 0; i < QB; ++i) keyp_lds[i][r] = acc[i];
      }
    }
    if (tid < QB) {   // c[qq] = key[qq]·b_v (b_v == 0 here; kept for generality)
      float s = 0.f;
      for (int e = 0; e < 128; e += 4) {
        const float4 bv = *(const float4*)(b_v + e);
        const float4 k4 = *(const float4*)(&key_lds[tid][e]);
        s = fmaf(bv.x, k4.x,
            fmaf(bv.y, k4.y, fmaf(bv.z, k4.z, fmaf(bv.w, k4.w, s))));
      }
      c_lds[tid] = s;
    }
  }
  __syncthreads();

  // ---- 4a. hoist A-fragments (keyp rows 0..3 padded to 16)
  bfx8 afrag[4];
  {
    const int row = l & 15, g = l >> 4;
#pragma unroll
    for (int ks = 0; ks < 4; ++ks) {
      bfx8 a;
      if (row < QB) {
        a = pack8(&keyp_lds[row][ks * 32 + g * 8]);
      } else {
#pragma unroll
        for (int j = 0; j < 8; ++j) a[j] = 0;
      }
      afrag[ks] = a;
    }
  }
  __syncthreads();   // keyp/sval reads done -> sval restaged below

  // ---- 4b. img = keyp·value^T + c  (8 tiles x 128 v-rows, thin MFMA)
  for (int vt = 0; vt < 8; ++vt) {
#pragma unroll
    for (int it = 0; it < 4; ++it) {
      const int c = tid + it * 512;          // 2048 chunks of 8 floats
      const int r = c >> 4, cc = c & 15;
      const bfx8 v = pack8(value + (size_t)(vt * 128 + r) * 128 + cc * 8);
      const int byte = r * 256 + ((cc * 16) ^ ((r & 15) << 4));
      *(bfx8*)((char*)sval + byte) = v;
    }
    __syncthreads();

    {
      const int col = l & 15, g = l >> 4;
      const int r = w * 16 + col;            // value row within tile
      f32x4 acc = {0.f, 0.f, 0.f, 0.f};
#pragma unroll
      for (int ks = 0; ks < 4; ++ks) {
        const int colb = (ks * 64 + g * 16) ^ (col << 4);
        const bfx8 bfr = *(const bfx8*)((const char*)sval + r * 256 + colb);
        acc = __builtin_amdgcn_mfma_f32_16x16x32_bf16(afrag[ks], bfr, acc,
                                                      0, 0, 0);
      }
      if (g == 0) {
        const int v = vt * 128 + r;
#pragma unroll
        for (int i = 0; i < QB; ++i)
          img_bf[i][v] = bf_rne(acc[i] + c_lds[i]);
      }
    }
    __syncthreads();
  }

  // ---- 5. sampling: (qq,d) = (tid>>7, tid&127), one pass over all 4 q
  {
    const int qq = tid >> 7;
    const int q = q0 + qq;
    const int d = tid & 127;
    const unsigned short* im = img_bf[qq];
    const size_t qe = (size_t)q * ND + d;

    const float rx = ref3d[qe * 2 + 0];
    const float ry = ref3d[qe * 2 + 1];

    const uint2 ua = *(const uint2*)(&aw_bf[qq][d * 4]);
    const float a0 = bf2f((unsigned short)(ua.x & 0xffff));
    const float a1 = bf2f((unsigned short)(ua.x >> 16));
    const float a2 = bf2f((unsigned short)(ua.y & 0xffff));
    const float a3 = bf2f((unsigned short)(ua.y >> 16));
    const float mx = fmaxf(fmaxf(a0, a1), fmaxf(a2, a3));
    const float e0 = __expf(a0 - mx), e1 = __expf(a1 - mx),
                e2 = __expf(a2 - mx), e3 = __expf(a3 - mx);
    const float inv = 1.0f / (e0 + e1 + e2 + e3);
    const float wgt4[4] = {e0 * inv, e1 * inv, e2 * inv, e3 * inv};

    const uint4 uo = *(const uint4*)(&off_bf[qq][d * 8]);
    const unsigned ox[4] = {uo.x, uo.y, uo.z, uo.w};

    float acc = 0.0f;
#pragma unroll
    for (int p = 0; p < NP; ++p) {
      const float x = rx * (float)IMG_W + bf2f((unsigned short)(ox[p] & 0xffff)) - 0.5f;
      const float y = ry * (float)IMG_H + bf2f((unsigned short)(ox[p] >> 16)) - 0.5f;
      const float xf = floorf(x), yf = floorf(y);
      const int ix0 = (int)xf, iy0 = (int)yf;
      const float wx1 = x - xf, wy1 = y - yf;
      const float wx0 = 1.0f - wx1, wy0 = 1.0f - wy1;

      float s = 0.0f;
#pragma unroll
      for (int cy = 0; cy < 2; ++cy) {
#pragma unroll
        for (int cx = 0; cx < 2; ++cx) {
          const int ix = ix0 + cx, iy = iy0 + cy;
          const bool valid = (ix >= 0) & (ix < IMG_W) & (iy >= 0) & (iy < IMG_H);
          const int cix = min(max(ix, 0), IMG_W - 1);
          const int ciy = min(max(iy, 0), IMG_H - 1);
          const float wgt = (cx ? wx1 : wx0) * (cy ? wy1 : wy0);
          s += valid ? bf2f(im[ciy * IMG_W + cix]) * wgt : 0.0f;
        }
      }
      acc += wgt4[p] * s;
    }
    __syncthreads();                     // sval MFMA reads done (last tile)
    o1s[qq * ND + d] = acc * (1.0f / 128.0f);   // o1s overlays dead sval
  }
  __syncthreads();

  // ---- 6. out[q][n] = o1s[q]·W_o[:,n] + b_o[n] + query[q][n]
  {
    const int qq = tid >> 7;
    const int n = tid & 127;
    float acc = b_o[n] + q_lds[qq][n];
#pragma unroll 8
    for (int d = 0; d < 128; ++d)
      acc = fmaf(o1s[qq * ND + d], W_o[(size_t)d * 128 + n], acc);
    out[(size_t)(q0 + qq) * 128 + n] = acc;
  }
}

// ---------------------------------------------------------------------------
extern "C" void kernel_launch(void* const* d_in, const int* in_sizes, int n_in,
                              void* d_out, int out_size, void* d_ws, size_t ws_size,
                              hipStream_t stream) {
  const float* query  = (const float*)d_in[0];
  const float* key    = (const float*)d_in[1];
  const float* value  = (const float*)d_in[2];
  const float* ref3d  = (const float*)d_in[3];
  // d_in[4] = spatial_shapes [[32,32]] (hardcoded)
  const float* W_off  = (const float*)d_in[5];
  const float* b_off  = (const float*)d_in[6];
  const float* W_attn = (const float*)d_in[7];
  const float* b_attn = (const float*)d_in[8];
  const float* W_v    = (const float*)d_in[9];
  const float* b_v    = (const float*)d_in[10];
  const float* W_o    = (const float*)d_in[11];
  const float* b_o    = (const float*)d_in[12];
  float* out = (float*)d_out;

  mono_kernel<<<NQ / QB, 512, 0, stream>>>(query, key, value, ref3d,
                                           W_off, b_off, W_attn, b_attn,
                                           W_v, b_v, W_o, b_o, out);
}

// Round 6
// 102.024 us; speedup vs baseline: 3.3943x; 1.0605x over previous
//
#include <hip/hip_runtime.h>

// UVCrossAttention — MI355X (gfx950), Round 9: wave-specialized monolith.
//
// R8 post-mortem: mono 42.7 µs at VALUBusy 24% / Occ 20%; dur(108.2) − mono
// = ~65 µs fixed harness residue. Per-CU L2 floor is ~11 µs; the 4x gap is
// the SERIAL phase chain (phase 2's 768 KB stream, then phase 4b's 512 KB
// stream + 16 barriers), each alone latency-bound. This round overlaps them:
//   waves 0-3: phase 2  (off/aw FMA streaming, R7-proven pattern, 256 thr)
//   waves 4-7: phase 4b (img thin-MFMA, wave-LOCAL 8 KB sval quarters,
//              ds_write->ds_read ordered by same-wave waitcnt, NO barriers)
// Block barriers: 5 total (was ~19). One dispatch, zero workspace.
// LDS 59.4 KB: q 2K | key 2K | keyp 2K | c 16B | img_bf 8K | off_bf 8K |
// aw_bf 4K | sval 32K (phase 3: W_v shared; phase 4b: 4x8K wave quarters;
// phase 5/6: o1s overlay). 256 blocks x 512 thr.

#define NQ   1024
#define NV   1024
#define ND   128
#define NP   4
#define IMG_W 32
#define IMG_H 32
#define QB   4

typedef __attribute__((ext_vector_type(8))) short bfx8;
typedef __attribute__((ext_vector_type(4))) float f32x4;

__device__ __forceinline__ unsigned short bf_rne(float f) {
  unsigned u = __float_as_uint(f);
  return (unsigned short)((u + 0x7FFFu + ((u >> 16) & 1u)) >> 16);
}
__device__ __forceinline__ float bf2f(unsigned short u) {
  return __uint_as_float((unsigned)u << 16);
}
__device__ __forceinline__ bfx8 pack8(const float* p) {
  bfx8 v;
#pragma unroll
  for (int j = 0; j < 8; ++j) v[j] = (short)bf_rne(p[j]);
  return v;
}

__global__ __launch_bounds__(512) void mono_kernel(
    const float* __restrict__ query, const float* __restrict__ key,
    const float* __restrict__ value, const float* __restrict__ ref3d,
    const float* __restrict__ W_off, const float* __restrict__ b_off,
    const float* __restrict__ W_attn, const float* __restrict__ b_attn,
    const float* __restrict__ W_v, const float* __restrict__ b_v,
    const float* __restrict__ W_o, const float* __restrict__ b_o,
    float* __restrict__ out) {
  __shared__ float q_lds[QB][128];                    // 2 KB
  __shared__ float key_lds[QB][128];                  // 2 KB
  __shared__ float keyp_lds[QB][128];                 // 2 KB
  __shared__ float c_lds[QB];
  __shared__ unsigned short img_bf[QB][NV];           // 8 KB
  __shared__ unsigned short off_bf[QB][1024];         // 8 KB
  __shared__ unsigned short aw_bf[QB][512];           // 4 KB
  __shared__ __align__(16) unsigned short sval[128 * 128];  // 32 KB
  float* o1s = (float*)sval;                          // phase 5/6 overlay

  const int tid = threadIdx.x;
  const int q0 = blockIdx.x * QB;
  const int w = tid >> 6, l = tid & 63;
  const int col = l & 15, g = l >> 4;

  // ---- 1. stage q, key, W_v (all independent, concurrent)
  if (tid < 128) {
    ((float4*)q_lds)[tid] = ((const float4*)(query + (size_t)q0 * 128))[tid];
  } else if (tid < 256) {
    ((float4*)key_lds)[tid - 128] =
        ((const float4*)(key + (size_t)q0 * 128))[tid - 128];
  }
#pragma unroll
  for (int it = 0; it < 4; ++it) {
    const int c = tid + it * 512;          // 2048 chunks of 8 floats
    const int r = c >> 4, cc = c & 15;
    const bfx8 v = pack8(W_v + (size_t)r * 128 + cc * 8);
    const int byte = r * 256 + ((cc * 16) ^ ((r & 15) << 4));
    *(bfx8*)((char*)sval + byte) = v;
  }
  __syncthreads();

  // ---- 2. keyp = key @ W_v^T (all 8 waves, wave w -> embed rows w*16..+15)
  {
    bfx8 afK[4];
#pragma unroll
    for (int ks = 0; ks < 4; ++ks) {
      bfx8 a;
      if (col < QB) {
        a = pack8(&key_lds[col][ks * 32 + g * 8]);
      } else {
#pragma unroll
        for (int j = 0; j < 8; ++j) a[j] = 0;
      }
      afK[ks] = a;
    }
    {
      const int r = w * 16 + col;          // W_v row = keyp embed index
      f32x4 acc = {0.f, 0.f, 0.f, 0.f};
#pragma unroll
      for (int ks = 0; ks < 4; ++ks) {
        const int colb = (ks * 64 + g * 16) ^ (col << 4);
        const bfx8 bfr = *(const bfx8*)((const char*)sval + r * 256 + colb);
        acc = __builtin_amdgcn_mfma_f32_16x16x32_bf16(afK[ks], bfr, acc,
                                                      0, 0, 0);
      }
      if (g == 0) {
#pragma unroll
        for (int i = 0; i < QB; ++i) keyp_lds[i][r] = acc[i];
      }
    }
    if (tid < QB) {   // c[qq] = key[qq]·b_v (b_v == 0 here; kept for generality)
      float s = 0.f;
      for (int e = 0; e < 128; e += 4) {
        const float4 bv = *(const float4*)(b_v + e);
        const float4 k4 = *(const float4*)(&key_lds[tid][e]);
        s = fmaf(bv.x, k4.x,
            fmaf(bv.y, k4.y, fmaf(bv.z, k4.z, fmaf(bv.w, k4.w, s))));
      }
      c_lds[tid] = s;
    }
  }
  __syncthreads();

  // ---- 3. SPLIT: waves 0-3 -> off/aw streaming; waves 4-7 -> img MFMA
  if (w < 4) {
    // phase 2: thread t (0..255) owns off cols 4t..4t+3, aw cols 2t..2t+1
    const int t = tid;
    float4 aoff[QB];
    float2 aaw[QB];
#pragma unroll
    for (int qq = 0; qq < QB; ++qq) {
      aoff[qq] = make_float4(0.f, 0.f, 0.f, 0.f);
      aaw[qq] = make_float2(0.f, 0.f);
    }
    const float* wo_p = W_off + (size_t)t * 4;
    const float* wa_p = W_attn + (size_t)t * 2;
#pragma unroll 4
    for (int e4 = 0; e4 < 32; ++e4) {
      float4 q4[QB];
#pragma unroll
      for (int qq = 0; qq < QB; ++qq)
        q4[qq] = *(const float4*)(&q_lds[qq][e4 * 4]);
#pragma unroll
      for (int j = 0; j < 4; ++j) {
        const int e = e4 * 4 + j;
        const float4 w4 = *(const float4*)(wo_p + (size_t)e * 1024);
        const float2 w2 = *(const float2*)(wa_p + (size_t)e * 512);
#pragma unroll
        for (int qq = 0; qq < QB; ++qq) {
          const float* qp = (const float*)&q4[qq];
          const float qv = qp[j];            // static extract (j unrolled)
          aoff[qq].x = fmaf(qv, w4.x, aoff[qq].x);
          aoff[qq].y = fmaf(qv, w4.y, aoff[qq].y);
          aoff[qq].z = fmaf(qv, w4.z, aoff[qq].z);
          aoff[qq].w = fmaf(qv, w4.w, aoff[qq].w);
          aaw[qq].x = fmaf(qv, w2.x, aaw[qq].x);
          aaw[qq].y = fmaf(qv, w2.y, aaw[qq].y);
        }
      }
    }
    const float4 bo4 = *(const float4*)(b_off + t * 4);
    const float2 ba2 = *(const float2*)(b_attn + t * 2);
#pragma unroll
    for (int qq = 0; qq < QB; ++qq) {
      const unsigned lo = (unsigned)bf_rne(aoff[qq].x + bo4.x) |
                          ((unsigned)bf_rne(aoff[qq].y + bo4.y) << 16);
      const unsigned hi = (unsigned)bf_rne(aoff[qq].z + bo4.z) |
                          ((unsigned)bf_rne(aoff[qq].w + bo4.w) << 16);
      *(uint2*)(&off_bf[qq][t * 4]) = make_uint2(lo, hi);
      *(unsigned*)(&aw_bf[qq][t * 2]) =
          (unsigned)bf_rne(aaw[qq].x + ba2.x) |
          ((unsigned)bf_rne(aaw[qq].y + ba2.y) << 16);
    }
  } else {
    // phase 4b: wave ww owns v rows ww*256..+255; 8 subtiles of 32 rows,
    // wave-local sval quarter (8 KB), NO block barriers in the loop.
    const int ww = w - 4;
    unsigned short* buf = sval + ww * 4096;
    bfx8 afrag[4];
#pragma unroll
    for (int ks = 0; ks < 4; ++ks) {
      bfx8 a;
      if (col < QB) {
        a = pack8(&keyp_lds[col][ks * 32 + g * 8]);
      } else {
#pragma unroll
        for (int j = 0; j < 8; ++j) a[j] = 0;
      }
      afrag[ks] = a;
    }
    float cq[QB];
#pragma unroll
    for (int i = 0; i < QB; ++i) cq[i] = c_lds[i];

    for (int sub = 0; sub < 8; ++sub) {
      const int vbase = ww * 256 + sub * 32;
      // stage 32 value rows -> bf16 swizzled into wave buffer
#pragma unroll
      for (int it = 0; it < 8; ++it) {
        const int c = l + it * 64;           // 0..511 chunks of 8
        const int r = c >> 4, cc = c & 15;
        const bfx8 v = pack8(value + (size_t)(vbase + r) * 128 + cc * 8);
        const int byte = r * 256 + ((cc * 16) ^ ((r & 15) << 4));
        *(bfx8*)((char*)buf + byte) = v;
      }
      // (same-wave ds_write->ds_read: compiler inserts lgkmcnt waits)
#pragma unroll
      for (int cg = 0; cg < 2; ++cg) {
        const int r = cg * 16 + col;         // row within 32-row subtile
        f32x4 acc = {0.f, 0.f, 0.f, 0.f};
#pragma unroll
        for (int ks = 0; ks < 4; ++ks) {
          const int colb = (ks * 64 + g * 16) ^ (col << 4);
          const bfx8 bfr = *(const bfx8*)((const char*)buf + r * 256 + colb);
          acc = __builtin_amdgcn_mfma_f32_16x16x32_bf16(afrag[ks], bfr, acc,
                                                        0, 0, 0);
        }
        if (g == 0) {
          const int v = vbase + r;
#pragma unroll
          for (int i = 0; i < QB; ++i)
            img_bf[i][v] = bf_rne(acc[i] + cq[i]);
        }
      }
    }
  }
  __syncthreads();

  // ---- 4. sampling: (qq,d) = (tid>>7, tid&127)
  {
    const int qq = tid >> 7;
    const int q = q0 + qq;
    const int d = tid & 127;
    const unsigned short* im = img_bf[qq];
    const size_t qe = (size_t)q * ND + d;

    const float rx = ref3d[qe * 2 + 0];
    const float ry = ref3d[qe * 2 + 1];

    const uint2 ua = *(const uint2*)(&aw_bf[qq][d * 4]);
    const float a0 = bf2f((unsigned short)(ua.x & 0xffff));
    const float a1 = bf2f((unsigned short)(ua.x >> 16));
    const float a2 = bf2f((unsigned short)(ua.y & 0xffff));
    const float a3 = bf2f((unsigned short)(ua.y >> 16));
    const float mx = fmaxf(fmaxf(a0, a1), fmaxf(a2, a3));
    const float e0 = __expf(a0 - mx), e1 = __expf(a1 - mx),
                e2 = __expf(a2 - mx), e3 = __expf(a3 - mx);
    const float inv = 1.0f / (e0 + e1 + e2 + e3);
    const float wgt4[4] = {e0 * inv, e1 * inv, e2 * inv, e3 * inv};

    const uint4 uo = *(const uint4*)(&off_bf[qq][d * 8]);
    const unsigned ox[4] = {uo.x, uo.y, uo.z, uo.w};

    float acc = 0.0f;
#pragma unroll
    for (int p = 0; p < NP; ++p) {
      const float x = rx * (float)IMG_W + bf2f((unsigned short)(ox[p] & 0xffff)) - 0.5f;
      const float y = ry * (float)IMG_H + bf2f((unsigned short)(ox[p] >> 16)) - 0.5f;
      const float xf = floorf(x), yf = floorf(y);
      const int ix0 = (int)xf, iy0 = (int)yf;
      const float wx1 = x - xf, wy1 = y - yf;
      const float wx0 = 1.0f - wx1, wy0 = 1.0f - wy1;

      float s = 0.0f;
#pragma unroll
      for (int cy = 0; cy < 2; ++cy) {
#pragma unroll
        for (int cx = 0; cx < 2; ++cx) {
          const int ix = ix0 + cx, iy = iy0 + cy;
          const bool valid = (ix >= 0) & (ix < IMG_W) & (iy >= 0) & (iy < IMG_H);
          const int cix = min(max(ix, 0), IMG_W - 1);
          const int ciy = min(max(iy, 0), IMG_H - 1);
          const float wgt = (cx ? wx1 : wx0) * (cy ? wy1 : wy0);
          s += valid ? bf2f(im[ciy * IMG_W + cix]) * wgt : 0.0f;
        }
      }
      acc += wgt4[p] * s;
    }
    o1s[qq * ND + (tid & 127)] = acc * (1.0f / 128.0f);  // overlays dead sval
  }
  __syncthreads();

  // ---- 5. out[q][n] = o1s[q]·W_o[:,n] + b_o[n] + query[q][n]
  {
    const int qq = tid >> 7;
    const int n = tid & 127;
    float acc = b_o[n] + q_lds[qq][n];
#pragma unroll 8
    for (int d = 0; d < 128; ++d)
      acc = fmaf(o1s[qq * ND + d], W_o[(size_t)d * 128 + n], acc);
    out[(size_t)(q0 + qq) * 128 + n] = acc;
  }
}

// ---------------------------------------------------------------------------
extern "C" void kernel_launch(void* const* d_in, const int* in_sizes, int n_in,
                              void* d_out, int out_size, void* d_ws, size_t ws_size,
                              hipStream_t stream) {
  const float* query  = (const float*)d_in[0];
  const float* key    = (const float*)d_in[1];
  const float* value  = (const float*)d_in[2];
  const float* ref3d  = (const float*)d_in[3];
  // d_in[4] = spatial_shapes [[32,32]] (hardcoded)
  const float* W_off  = (const float*)d_in[5];
  const float* b_off  = (const float*)d_in[6];
  const float* W_attn = (const float*)d_in[7];
  const float* b_attn = (const float*)d_in[8];
  const float* W_v    = (const float*)d_in[9];
  const float* b_v    = (const float*)d_in[10];
  const float* W_o    = (const float*)d_in[11];
  const float* b_o    = (const float*)d_in[12];
  float* out = (float*)d_out;

  mono_kernel<<<NQ / QB, 512, 0, stream>>>(query, key, value, ref3d,
                                           W_off, b_off, W_attn, b_attn,
                                           W_v, b_v, W_o, b_o, out);
}